// Round 13
// baseline (20.456 us; speedup 1.0000x reference)
//
#include <hip/hip_runtime.h>
#include <cstdint>
#include <cstddef>

#define BATCH 4
#define NTOK  4096
#define CCH   256
#define IMH   512
#define IMW   512
#define PMAXV 124
#define NCELLS (PMAXV * PMAXV)                  // 15376 cells per batch

#define RPB 8
#define GATHER_BLOCKS (BATCH * NTOK / RPB)      // 2048

#define CELL_THREADS (BATCH * NCELLS)           // 61504
#define CELL_BLOCKS  ((CELL_THREADS + 255) / 256)   // 241
#define BUILD_BLOCKS (BATCH * NTOK / 256)       // 64

typedef float v4f __attribute__((ext_vector_type(4)));

// ---------------------------------------------------------------------------
// Structural insight: patches tile a 124x124 cell grid (p_org = pos*4, 4x4
// patch, min_patch=4). So dis is a pure function of the cell -> precompute
// dis_cell[b][cy][cx] once (coalesced), then dis[b,i] is ONE 4B lookup.
// Match is a global first-occurrence table (argmin L1 == first exact match,
// since pos_shuffled is a permutation of pos_org).
// ---------------------------------------------------------------------------

// K0: table init (d_ws not re-poisoned between replays -> init every call)
__global__ __launch_bounds__(256) void init_k(int* __restrict__ table) {
    int t = blockIdx.x * 256 + threadIdx.x;
    if (t < CELL_THREADS) table[t] = 0x7FFFFFFF;
}

// K1: blocks [0,CELL_BLOCKS) -> dis_cell; blocks [CELL_BLOCKS,+64) -> table build
__global__ __launch_bounds__(256) void cell_build_k(const float* __restrict__ im,
                                                    const int2* __restrict__ ps,
                                                    int* __restrict__ table,
                                                    float* __restrict__ cell) {
    const int tid = threadIdx.x;

    if (blockIdx.x >= CELL_BLOCKS) {
        // ---- table build: first-occurrence index per cell key ----
        const int bt = (blockIdx.x - CELL_BLOCKS) * 256 + tid;   // 0..16383
        const int b  = bt >> 12;
        const int j  = bt & (NTOK - 1);
        const int2 p = ps[bt];
        atomicMin(&table[b * NCELLS + p.x * PMAXV + p.y], j);
        return;
    }

    // ---- dis_cell: one thread per cell, coalesced float4 stencil ----
    const int t = blockIdx.x * 256 + tid;
    if (t >= CELL_THREADS) return;
    const int b  = t / NCELLS;
    const int r  = t - b * NCELLS;
    const int cy = r / PMAXV;
    const int cx = r - cy * PMAXV;
    const int row0 = cy * 4;                    // pixel rows row0..row0+3 (<=495)
    const int col0 = cx * 4;                    // 16B-aligned col base (<=492)

    float acc = 0.f;
#pragma unroll
    for (int ch = 0; ch < 3; ++ch) {
        const float* p = im + (((size_t)(b * 3 + ch)) * IMH + row0) * IMW + col0;
        // rows: R[0]=halo top (clamped), R[1..4]=pixel rows, R[5]=halo bottom
        v4f R0 = *(const v4f*)(row0 > 0 ? p - IMW : p);
        v4f R1 = *(const v4f*)(p);
        v4f R2 = *(const v4f*)(p + IMW);
        v4f R3 = *(const v4f*)(p + 2 * IMW);
        v4f R4 = *(const v4f*)(p + 3 * IMW);
        v4f R5 = *(const v4f*)(p + 4 * IMW);    // row0+4 <= 496, valid
        float L0 = 0, L1 = 0, L2 = 0, L3 = 0;
        if (col0 > 0) { L0 = p[-1]; L1 = p[IMW - 1]; L2 = p[2*IMW - 1]; L3 = p[3*IMW - 1]; }
        const float E0 = p[4], E1 = p[IMW + 4], E2 = p[2*IMW + 4], E3 = p[3*IMW + 4];

        // vertical: dv(R0,R1)*1 (if top halo real) + 2*(dv12+dv23+dv34) + dv45*1
        #define DV(a, b_) (fabsf((b_).x-(a).x)+fabsf((b_).y-(a).y)+fabsf((b_).z-(a).z)+fabsf((b_).w-(a).w))
        if (row0 > 0) acc += DV(R0, R1);
        acc += 2.f * (DV(R1, R2) + DV(R2, R3) + DV(R3, R4));
        acc += DV(R4, R5);
        #undef DV

        // horizontal per pixel row: 2*(internal diffs) + left edge (clipped) + right edge
        #define DH(Rw, Lv, Ev) do { \
            acc += 2.f * (fabsf((Rw).y-(Rw).x) + fabsf((Rw).z-(Rw).y) + fabsf((Rw).w-(Rw).z)); \
            if (col0 > 0) acc += fabsf((Rw).x - (Lv)); \
            acc += fabsf((Ev) - (Rw).w); \
        } while (0)
        DH(R1, L0, E0); DH(R2, L1, E1); DH(R3, L2, E2); DH(R4, L3, E3);
        #undef DH
    }
    cell[t] = acc;
}

// K2: pure gather + single-lookup idx/dis. RPB=8, 2048 blocks (proven optimum).
__global__ __launch_bounds__(256) void gather_k(const float4* __restrict__ feat,
                                                const int2* __restrict__ po,
                                                const int* __restrict__ table,
                                                const float* __restrict__ cell,
                                                float4* __restrict__ out_feat,
                                                float* __restrict__ out_dis) {
    __shared__ int s_idx[RPB];

    const int tid = threadIdx.x;
    const int r0  = blockIdx.x * RPB;
    const int b   = blockIdx.x >> 9;            // 512 blocks per batch

    if (tid < RPB) {
        const int2 p = po[r0 + tid];
        s_idx[tid] = table[b * NCELLS + p.x * PMAXV + p.y];
        const float dv = cell[b * NCELLS + p.y * PMAXV + p.x];  // cell[cy][cx]
        __builtin_nontemporal_store(dv, &out_dis[r0 + tid]);
    }
    __syncthreads();

    const int lane = tid & 63;
    const int w    = tid >> 6;
    const int row0 = r0 + w * 2, row1 = row0 + 1;
    const int idx0 = s_idx[w * 2], idx1 = s_idx[w * 2 + 1];

    const float4 f0 = feat[((size_t)(b * NTOK + idx0)) * 64 + lane];
    const float4 f1 = feat[((size_t)(b * NTOK + idx1)) * 64 + lane];
    v4f n0 = { f0.x, f0.y, f0.z, f0.w };
    v4f n1 = { f1.x, f1.y, f1.z, f1.w };
    __builtin_nontemporal_store(n0, (v4f*)&out_feat[(size_t)row0 * 64 + lane]);
    __builtin_nontemporal_store(n1, (v4f*)&out_feat[(size_t)row1 * 64 + lane]);
}

extern "C" void kernel_launch(void* const* d_in, const int* in_sizes, int n_in,
                              void* d_out, int out_size, void* d_ws, size_t ws_size,
                              hipStream_t stream) {
    const float* feat         = (const float*)d_in[0];
    const float* images       = (const float*)d_in[1];
    const int*   pos_org      = (const int*)d_in[2];
    const int*   pos_shuffled = (const int*)d_in[3];

    float* out_feat = (float*)d_out;
    float* out_dis  = out_feat + (size_t)BATCH * NTOK * CCH;

    int*   table = (int*)d_ws;                        // 246 KB
    float* cell  = (float*)d_ws + CELL_THREADS;       // 246 KB

    init_k<<<CELL_BLOCKS, 256, 0, stream>>>(table);
    cell_build_k<<<CELL_BLOCKS + BUILD_BLOCKS, 256, 0, stream>>>(
        images, (const int2*)pos_shuffled, table, cell);
    gather_k<<<GATHER_BLOCKS, 256, 0, stream>>>(
        (const float4*)feat, (const int2*)pos_org, table, cell,
        (float4*)out_feat, out_dis);
}